// Round 7
// baseline (625.088 us; speedup 1.0000x reference)
//
#include <hip/hip_runtime.h>
#include <hip/hip_fp16.h>
#include <math.h>

#define B_SZ 64
#define T_SZ 512
#define M_TOT (B_SZ * T_SZ)   // 32768 tokens
#define HSTR  160             // uints per weight row (320 halves; rows/cols >=300 zero)
#define NPASS 11              // fixed-point refinement passes (halo 16 >= NPASS)
#define BROW  332             // halves per LDS G row: 166 uints == 6 mod 32 -> ~2-way banks
#define NEGB  -60000.0f       // pad-bias poison: relu->0, sigm->0

typedef _Float16 f16x8 __attribute__((ext_vector_type(8)));
typedef float    f32x4 __attribute__((ext_vector_type(4)));

__device__ __forceinline__ unsigned int packrte(float a, float b) {
    __half2 h = __floats2half2_rn(a, b);
    return __builtin_bit_cast(unsigned int, h);
}
// rcp-based sigmoid: output is f16-rounded downstream, so rcp's ~1ulp f32
// error is invisible; pads: exp(60000)=inf -> rcp(inf)=0 exactly.
// (validated in round 6: absmax unchanged, VALU-cycles halved)
__device__ __forceinline__ float sigm(float v) {
    return __builtin_amdgcn_rcpf(1.f + __expf(-v));
}

// =====================================================================
// Weights fp32 -> packed f16x2, zero-padded to 320x320.  m=4: padded
// bias vectors (pads poisoned with NEGB so relu/sigm give exact 0).
// =====================================================================
__global__ __launch_bounds__(160) void wconv(
    const float* __restrict__ fc1_w, const float* __restrict__ l1_w,
    const float* __restrict__ l2_w, const float* __restrict__ fc1_b,
    const float* __restrict__ l1_b, const float* __restrict__ l2_b,
    unsigned int* __restrict__ Wh, float* __restrict__ BP)
{
    const int r = blockIdx.x, m = blockIdx.y, j = threadIdx.x;
    if (m == 4) {
        if (j == 0) BP[r]       = (r < 300) ? fc1_b[r] : NEGB;
        if (j == 1) BP[320 + r] = (r < 300) ? l1_b[r]  : NEGB;
        if (j == 2) BP[640 + r] = (r < 300) ? l2_b[r]  : 0.f;
        return;
    }
    const float* src; int stride, off;
    if (m == 0)      { src = fc1_w; stride = 300; off = 0; }
    else if (m == 1) { src = l1_w;  stride = 600; off = 0; }
    else if (m == 2) { src = l2_w;  stride = 300; off = 0; }
    else             { src = l1_w;  stride = 600; off = 300; }
    int k = 2 * j;
    bool rv = (r < 300);
    float a = (rv && k     < 300) ? src[(long)r * stride + off + k]     : 0.f;
    float b = (rv && k + 1 < 300) ? src[(long)r * stride + off + k + 1] : 0.f;
    Wh[((long)m * 320 + r) * HSTR + j] = packrte(a, b);
}

// =====================================================================
// Fused per-64-row-tile kernel: 10 waves (640 thr), round-4 shell
// (in-place G buffer, 2 barriers/pass — the verified 305us structure).
// NEW: the wave's Whh slice (2 rows x 320 halves = 20 uint4 = 80 VGPRs)
// is loaded ONCE into registers before the RNN loop; the 11 RNN GEMMs
// are pure LDS+MFMA with zero global loads (kills the per-kc L2 chain).
// Swapped MFMA: A = weight frag (16 out cols), B = G frag (16 tokens).
// D: col(ml)=token, row(q*4+r)=out col -> packed ds_write_b64 updates.
// =====================================================================
__global__ __launch_bounds__(640, 3) void rnn_mega(
    const int* __restrict__ x, const float* __restrict__ emb,
    const float* __restrict__ BP, const unsigned int* __restrict__ Wh,
    float* __restrict__ part)
{
    __shared__ _Float16 Gt[81 * BROW];   // row 0 = zero shift-source

    const int tid  = threadIdx.x;
    const int lane = tid & 63;
    const int ml   = lane & 15;
    const int q    = lane >> 4;
    const int c0   = (tid >> 6) * 32;    // wave's 32 output cols
    const int m0   = blockIdx.x * 64;
    const int m0h  = m0 - 16;
    const bool bstart = (m0 & (T_SZ - 1)) == 0;
    const unsigned int killm = (bstart && ml == 15) ? 0u : ~0u;  // row t=m0-1

    const uint4* Wq = (const uint4*)Wh;             // 40 uint4 per row
    const float* bpf  = BP;
    const float* bpl1 = BP + 320;
    const float* bpl2 = BP + 640;

    // per-wave LDS bases (all hot accesses = base + compile-time offset)
    const _Float16* grd = &Gt[ml * BROW + q * 8];             // B-frag reads
    _Float16*       gwr = &Gt[(ml + 1) * BROW + c0 + q * 4];  // update writes

    // ---- stage emb[x[m0h..m0h+80)] as f16 into Gt rows 1..80
    #pragma unroll
    for (int it = 0; it < 5; ++it) {
        int li  = it * 640 + tid;      // 0..3199
        int row = li / 40;             // 0..79
        int sg  = li % 40;             // 8-half segment
        int g   = m0h + row; if (g < 0) g = 0;   // block 0 halo clamp
        const float* er = emb + (long)x[g] * 300;
        int k = sg * 8;
        float4 f0 = (k + 4 <= 300) ? *(const float4*)(er + k)     : make_float4(0,0,0,0);
        float4 f1 = (k + 8 <= 300) ? *(const float4*)(er + k + 4) : make_float4(0,0,0,0);
        *(uint4*)&Gt[(row + 1) * BROW + sg * 8] =
            make_uint4(packrte(f0.x, f0.y), packrte(f0.z, f0.w),
                       packrte(f1.x, f1.y), packrte(f1.z, f1.w));
    }
    if (tid < 42) *(uint4*)&Gt[tid * 8] = make_uint4(0, 0, 0, 0);  // row 0 = 0
    __syncthreads();

    f32x4        acc[5][2];
    unsigned int xpk[5][2][2];

    // GEMM (global-weight path, used for fc1/l1x/l2 only):
    // A-frags (weights) from L2 double-buffered one kc ahead; B-frags
    // ds_read_b128 at immediate offsets, double-buffered one kc ahead.
    #define RUN_GEMM(WQ, RO, MT0) do {                                        \
        _Pragma("unroll") for (int mt = (MT0); mt < 5; ++mt)                  \
        _Pragma("unroll") for (int nt = 0; nt < 2; ++nt)                      \
            acc[mt][nt] = (f32x4){0.f, 0.f, 0.f, 0.f};                        \
        const uint4* wp0_ = (WQ) + (c0 + ml) * 40 + q;                        \
        const uint4* wp1_ = wp0_ + 640;                                       \
        uint4 a0_ = wp0_[0], a1_ = wp1_[0];                                   \
        f16x8 bc_[5];                                                         \
        _Pragma("unroll") for (int mt = (MT0); mt < 5; ++mt)                  \
            bc_[mt] = *(const f16x8*)(grd + (mt * 16 + (RO)) * BROW);         \
        _Pragma("unroll") for (int kc = 0; kc < 10; ++kc) {                   \
            uint4 an0_, an1_; f16x8 bn_[5];                                   \
            if (kc < 9) {                                                     \
                an0_ = wp0_[(kc + 1) * 4];                                    \
                an1_ = wp1_[(kc + 1) * 4];                                    \
                _Pragma("unroll") for (int mt = (MT0); mt < 5; ++mt)          \
                    bn_[mt] = *(const f16x8*)(grd + (mt * 16 + (RO)) * BROW   \
                                              + (kc + 1) * 32);               \
            }                                                                 \
            _Pragma("unroll") for (int mt = (MT0); mt < 5; ++mt) {            \
                acc[mt][0] = __builtin_amdgcn_mfma_f32_16x16x32_f16(          \
                    __builtin_bit_cast(f16x8, a0_), bc_[mt], acc[mt][0],      \
                    0, 0, 0);                                                 \
                acc[mt][1] = __builtin_amdgcn_mfma_f32_16x16x32_f16(          \
                    __builtin_bit_cast(f16x8, a1_), bc_[mt], acc[mt][1],      \
                    0, 0, 0);                                                 \
            }                                                                 \
            a0_ = an0_; a1_ = an1_;                                           \
            _Pragma("unroll") for (int mt = (MT0); mt < 5; ++mt)              \
                bc_[mt] = bn_[mt];                                            \
        } } while (0)

    // GEMM (register-weight path, the 11 RNN passes): weights wh0/wh1
    // already in VGPRs -> zero global loads, pure ds_read + MFMA.
    #define RUN_GEMM_R(RO, MT0) do {                                          \
        _Pragma("unroll") for (int mt = (MT0); mt < 5; ++mt)                  \
        _Pragma("unroll") for (int nt = 0; nt < 2; ++nt)                      \
            acc[mt][nt] = (f32x4){0.f, 0.f, 0.f, 0.f};                        \
        _Pragma("unroll") for (int kc = 0; kc < 10; ++kc)                     \
        _Pragma("unroll") for (int mt = (MT0); mt < 5; ++mt) {                \
            f16x8 bg_ = *(const f16x8*)(grd + (mt * 16 + (RO)) * BROW         \
                                        + kc * 32);                           \
            acc[mt][0] = __builtin_amdgcn_mfma_f32_16x16x32_f16(              \
                __builtin_bit_cast(f16x8, wh0[kc]), bg_, acc[mt][0],          \
                0, 0, 0);                                                     \
            acc[mt][1] = __builtin_amdgcn_mfma_f32_16x16x32_f16(              \
                __builtin_bit_cast(f16x8, wh1[kc]), bg_, acc[mt][1],          \
                0, 0, 0);                                                     \
        } } while (0)

    // sigmoid update: G[token row] cols = sigm(acc + xp), packed b64 store
    #define UPDATE_G(MT0) do {                                                \
        _Pragma("unroll") for (int mt = (MT0); mt < 5; ++mt)                  \
        _Pragma("unroll") for (int nt = 0; nt < 2; ++nt) {                    \
            __half2 plo = __builtin_bit_cast(__half2, xpk[mt][nt][0]);        \
            __half2 phi = __builtin_bit_cast(__half2, xpk[mt][nt][1]);        \
            float v0 = sigm(acc[mt][nt][0] + __low2float(plo));               \
            float v1 = sigm(acc[mt][nt][1] + __high2float(plo));              \
            float v2 = sigm(acc[mt][nt][2] + __low2float(phi));               \
            float v3 = sigm(acc[mt][nt][3] + __high2float(phi));              \
            unsigned int p0 = packrte(v0, v1), p1 = packrte(v2, v3);          \
            if (mt == 0) { p0 &= killm; p1 &= killm; }                        \
            *(uint2*)(gwr + mt * 16 * BROW + nt * 16) = make_uint2(p0, p1);   \
        } } while (0)

    // ---- h = relu(embf16 @ fc1.T + fc1_b) -> Gt rows 1..80 (in place)
    RUN_GEMM(Wq, 1, 0);
    __syncthreads();                  // all waves done reading staged emb
    #pragma unroll
    for (int nt = 0; nt < 2; ++nt) {
        float4 bb = *(const float4*)(bpf + c0 + nt * 16 + q * 4);
        #pragma unroll
        for (int mt = 0; mt < 5; ++mt) {
            float v0 = fmaxf(acc[mt][nt][0] + bb.x, 0.f);
            float v1 = fmaxf(acc[mt][nt][1] + bb.y, 0.f);
            float v2 = fmaxf(acc[mt][nt][2] + bb.z, 0.f);
            float v3 = fmaxf(acc[mt][nt][3] + bb.w, 0.f);
            *(uint2*)(gwr + mt * 16 * BROW + nt * 16) =
                make_uint2(packrte(v0, v1), packrte(v2, v3));
        }
    }
    __syncthreads();

    // ---- xp = h @ l1_wx.T + l1_b, packed f16 in regs (pads = NEGB)
    RUN_GEMM(Wq + 320 * 40, 1, 0);
    #pragma unroll
    for (int nt = 0; nt < 2; ++nt) {
        float4 bb = *(const float4*)(bpl1 + c0 + nt * 16 + q * 4);
        #pragma unroll
        for (int mt = 0; mt < 5; ++mt) {
            xpk[mt][nt][0] = packrte(acc[mt][nt][0] + bb.x, acc[mt][nt][1] + bb.y);
            xpk[mt][nt][1] = packrte(acc[mt][nt][2] + bb.z, acc[mt][nt][3] + bb.w);
        }
    }

    // ---- persistent Whh slice -> registers (once; reused by 11 passes)
    uint4 wh0[10], wh1[10];
    {
        const uint4* whp = Wq + 3 * 320 * 40 + (c0 + ml) * 40 + q;
        #pragma unroll
        for (int kc = 0; kc < 10; ++kc) {
            wh0[kc] = whp[kc * 4];
            wh1[kc] = whp[640 + kc * 4];
        }
    }

    __syncthreads();                  // all waves done reading h
    // ---- G init = sigm(xp)  (pads -> sigm(NEGB) = 0)
    #pragma unroll
    for (int mt = 0; mt < 5; ++mt)
    #pragma unroll
    for (int nt = 0; nt < 2; ++nt) {
        __half2 plo = __builtin_bit_cast(__half2, xpk[mt][nt][0]);
        __half2 phi = __builtin_bit_cast(__half2, xpk[mt][nt][1]);
        unsigned int p0 = packrte(sigm(__low2float(plo)), sigm(__high2float(plo)));
        unsigned int p1 = packrte(sigm(__low2float(phi)), sigm(__high2float(phi)));
        if (mt == 0) { p0 &= killm; p1 &= killm; }
        *(uint2*)(gwr + mt * 16 * BROW + nt * 16) = make_uint2(p0, p1);
    }
    __syncthreads();

    // ---- 11 fixed-point passes, all in LDS, weights in registers
    #pragma unroll 1
    for (int p = 0; p < NPASS; ++p) {
        if (p == NPASS - 1) {         // last pass: halo rows dead
            RUN_GEMM_R(0, 1);
            __syncthreads();
            UPDATE_G(1);
        } else {
            RUN_GEMM_R(0, 0);
            __syncthreads();
            UPDATE_G(0);
        }
        __syncthreads();
    }

    // ---- out = G @ l2.T over output tokens (mt 1..4 = rows m0..m0+63);
    //      max over tokens = in-lane over mt + shfl over ml lanes
    RUN_GEMM(Wq + 2 * 320 * 40, 1, 1);
    #pragma unroll
    for (int nt = 0; nt < 2; ++nt)
    #pragma unroll
    for (int r = 0; r < 4; ++r) {
        float v = acc[1][nt][r];
        v = fmaxf(v, acc[2][nt][r]);
        v = fmaxf(v, acc[3][nt][r]);
        v = fmaxf(v, acc[4][nt][r]);
        v = fmaxf(v, __shfl_xor(v, 1));
        v = fmaxf(v, __shfl_xor(v, 2));
        v = fmaxf(v, __shfl_xor(v, 4));
        v = fmaxf(v, __shfl_xor(v, 8));
        if (ml == 0) {
            int col = c0 + nt * 16 + q * 4 + r;
            part[(long)blockIdx.x * 320 + col] = v + bpl2[col];
        }
    }
    #undef RUN_GEMM
    #undef RUN_GEMM_R
    #undef UPDATE_G
}

// =====================================================================
// Final: pooled[b,n] = max over 8 m-chunks of part; out = pooled @ fc2_w.T
// =====================================================================
__global__ __launch_bounds__(320) void fc2_final(
    const float* __restrict__ part,     // [512, 320]
    const float* __restrict__ fc2_w,
    const float* __restrict__ fc2_b,
    float* __restrict__ out)
{
    const int b   = blockIdx.x;
    const int tid = threadIdx.x;
    __shared__ float pooled[304];

    if (tid < 300) {
        float m = part[(long)(b * 8) * 320 + tid];
        #pragma unroll
        for (int c = 1; c < 8; c++)
            m = fmaxf(m, part[(long)(b * 8 + c) * 320 + tid]);
        pooled[tid] = m;
    }
    __syncthreads();

    const int o    = tid >> 6;
    const int lane = tid & 63;
    if (o < 2) {
        float sacc = 0.f;
        for (int jj = lane; jj < 300; jj += 64)
            sacc += pooled[jj] * fc2_w[o * 300 + jj];
        #pragma unroll
        for (int off = 32; off > 0; off >>= 1)
            sacc += __shfl_down(sacc, off);
        if (lane == 0) out[b * 2 + o] = sacc + fc2_b[o];
    }
}

// =====================================================================
extern "C" void kernel_launch(void* const* d_in, const int* in_sizes, int n_in,
                              void* d_out, int out_size, void* d_ws, size_t ws_size,
                              hipStream_t stream)
{
    const int*   x     = (const int*)  d_in[0];
    const float* emb   = (const float*)d_in[1];
    const float* fc1_w = (const float*)d_in[2];
    const float* fc1_b = (const float*)d_in[3];
    const float* l1_w  = (const float*)d_in[4];
    const float* l1_b  = (const float*)d_in[5];
    const float* l2_w  = (const float*)d_in[6];
    const float* l2_b  = (const float*)d_in[7];
    const float* fc2_w = (const float*)d_in[8];
    const float* fc2_b = (const float*)d_in[9];
    float* out = (float*)d_out;

    // ws: part [512*320 f32] | Wh [4*320*160 uints] | BP [960 f32]
    float* part = (float*)d_ws;
    unsigned int* Wh = (unsigned int*)(part + (size_t)512 * 320);
    float* BP = (float*)(Wh + (size_t)4 * 320 * HSTR);

    wconv<<<dim3(320, 5), 160, 0, stream>>>(
        fc1_w, l1_w, l2_w, fc1_b, l1_b, l2_b, Wh, BP);
    rnn_mega<<<M_TOT / 64, 640, 0, stream>>>(x, emb, BP, Wh, part);
    fc2_final<<<B_SZ, 320, 0, stream>>>(part, fc2_w, fc2_b, out);
}

// Round 8
// 605.756 us; speedup vs baseline: 1.0319x; 1.0319x over previous
//
#include <hip/hip_runtime.h>
#include <hip/hip_fp16.h>
#include <math.h>

#define B_SZ 64
#define T_SZ 512
#define M_TOT (B_SZ * T_SZ)   // 32768 tokens
#define HSTR  160             // uints per weight row (320 halves; rows/cols >=300 zero)
#define NPASS 11              // fixed-point refinement passes (halo 16 >= NPASS)
#define BROW  332             // halves per LDS G row: 166 uints == 6 mod 32 (validated r6:
                              //   bank conflicts 1.65e7 -> 1.67e5 vs BROW=328)
#define NEGB  -60000.0f       // pad-bias poison: relu->0, sigm->0

typedef _Float16 f16x8 __attribute__((ext_vector_type(8)));
typedef float    f32x4 __attribute__((ext_vector_type(4)));

__device__ __forceinline__ unsigned int packrte(float a, float b) {
    __half2 h = __floats2half2_rn(a, b);
    return __builtin_bit_cast(unsigned int, h);
}
// rcp-based sigmoid (validated r6/r7: absmax unchanged, VALU work halved).
// Output is f16-rounded downstream so rcp's ~1ulp f32 error is invisible;
// pads: exp(60000)=inf -> rcp(inf)=0 exactly.
__device__ __forceinline__ float sigm(float v) {
    return __builtin_amdgcn_rcpf(1.f + __expf(-v));
}

// =====================================================================
// Weights fp32 -> packed f16x2, zero-padded to 320x320.  m=4: padded
// bias vectors (pads poisoned with NEGB so relu/sigm give exact 0).
// =====================================================================
__global__ __launch_bounds__(160) void wconv(
    const float* __restrict__ fc1_w, const float* __restrict__ l1_w,
    const float* __restrict__ l2_w, const float* __restrict__ fc1_b,
    const float* __restrict__ l1_b, const float* __restrict__ l2_b,
    unsigned int* __restrict__ Wh, float* __restrict__ BP)
{
    const int r = blockIdx.x, m = blockIdx.y, j = threadIdx.x;
    if (m == 4) {
        if (j == 0) BP[r]       = (r < 300) ? fc1_b[r] : NEGB;
        if (j == 1) BP[320 + r] = (r < 300) ? l1_b[r]  : NEGB;
        if (j == 2) BP[640 + r] = (r < 300) ? l2_b[r]  : 0.f;
        return;
    }
    const float* src; int stride, off;
    if (m == 0)      { src = fc1_w; stride = 300; off = 0; }
    else if (m == 1) { src = l1_w;  stride = 600; off = 0; }
    else if (m == 2) { src = l2_w;  stride = 300; off = 0; }
    else             { src = l1_w;  stride = 600; off = 300; }
    int k = 2 * j;
    bool rv = (r < 300);
    float a = (rv && k     < 300) ? src[(long)r * stride + off + k]     : 0.f;
    float b = (rv && k + 1 < 300) ? src[(long)r * stride + off + k + 1] : 0.f;
    Wh[((long)m * 320 + r) * HSTR + j] = packrte(a, b);
}

// =====================================================================
// Fused per-64-row-tile kernel: 10 waves (640 thr) — the verified
// round-4 shell (in-place G buffer, 2 barriers/pass, VGPR 84, no spill)
// with ONLY the two individually-validated micro-opts applied:
// BROW=332 (bank-conflict kill) and rcp-sigmoid (VALU halving).
// Swapped MFMA: A = weight frag (16 out cols), B = G frag (16 tokens).
// D: col(ml)=token, row(q*4+r)=out col -> packed ds_write_b64 updates.
// Wave owns 32 output cols (nt=2), loops all 5 m-tiles.
// =====================================================================
__global__ __launch_bounds__(640, 3) void rnn_mega(
    const int* __restrict__ x, const float* __restrict__ emb,
    const float* __restrict__ BP, const unsigned int* __restrict__ Wh,
    float* __restrict__ part)
{
    __shared__ _Float16 Gt[81 * BROW];   // row 0 = zero shift-source

    const int tid  = threadIdx.x;
    const int lane = tid & 63;
    const int ml   = lane & 15;
    const int q    = lane >> 4;
    const int c0   = (tid >> 6) * 32;    // wave's 32 output cols
    const int m0   = blockIdx.x * 64;
    const int m0h  = m0 - 16;
    const bool bstart = (m0 & (T_SZ - 1)) == 0;
    const unsigned int killm = (bstart && ml == 15) ? 0u : ~0u;  // row t=m0-1

    const uint4* Wq = (const uint4*)Wh;             // 40 uint4 per row
    const float* bpf  = BP;
    const float* bpl1 = BP + 320;
    const float* bpl2 = BP + 640;

    // per-wave LDS bases (all hot accesses = base + compile-time offset)
    const _Float16* grd = &Gt[ml * BROW + q * 8];             // B-frag reads
    _Float16*       gwr = &Gt[(ml + 1) * BROW + c0 + q * 4];  // update writes

    // ---- zero shift-source row 0 (exactly BROW halves = 166 uints)
    if (tid < 166) ((unsigned int*)Gt)[tid] = 0u;
    // ---- stage emb[x[m0h..m0h+80)] as f16 into Gt rows 1..80
    #pragma unroll
    for (int it = 0; it < 5; ++it) {
        int li  = it * 640 + tid;      // 0..3199
        int row = li / 40;             // 0..79
        int sg  = li % 40;             // 8-half segment
        int g   = m0h + row; if (g < 0) g = 0;   // block 0 halo clamp
        const float* er = emb + (long)x[g] * 300;
        int k = sg * 8;
        float4 f0 = (k + 4 <= 300) ? *(const float4*)(er + k)     : make_float4(0,0,0,0);
        float4 f1 = (k + 8 <= 300) ? *(const float4*)(er + k + 4) : make_float4(0,0,0,0);
        *(uint4*)&Gt[(row + 1) * BROW + sg * 8] =
            make_uint4(packrte(f0.x, f0.y), packrte(f0.z, f0.w),
                       packrte(f1.x, f1.y), packrte(f1.z, f1.w));
    }
    __syncthreads();

    f32x4        acc[5][2];
    unsigned int xpk[5][2][2];

    // GEMM: acc[mt][nt] = W(rows c0+nt*16..) @ Gt(rows mt*16+ml+RO).T
    // A-frags (weights) from L2, B-frags ds_read_b128 at immediate
    // offsets, both register-double-buffered one kc ahead.
    #define RUN_GEMM(WQ, RO, MT0) do {                                        \
        _Pragma("unroll") for (int mt = (MT0); mt < 5; ++mt)                  \
        _Pragma("unroll") for (int nt = 0; nt < 2; ++nt)                      \
            acc[mt][nt] = (f32x4){0.f, 0.f, 0.f, 0.f};                        \
        const uint4* wp0_ = (WQ) + (c0 + ml) * 40 + q;                        \
        const uint4* wp1_ = wp0_ + 640;                                       \
        uint4 a0_ = wp0_[0], a1_ = wp1_[0];                                   \
        f16x8 bc_[5];                                                         \
        _Pragma("unroll") for (int mt = (MT0); mt < 5; ++mt)                  \
            bc_[mt] = *(const f16x8*)(grd + (mt * 16 + (RO)) * BROW);         \
        _Pragma("unroll") for (int kc = 0; kc < 10; ++kc) {                   \
            uint4 an0_, an1_; f16x8 bn_[5];                                   \
            if (kc < 9) {                                                     \
                an0_ = wp0_[(kc + 1) * 4];                                    \
                an1_ = wp1_[(kc + 1) * 4];                                    \
                _Pragma("unroll") for (int mt = (MT0); mt < 5; ++mt)          \
                    bn_[mt] = *(const f16x8*)(grd + (mt * 16 + (RO)) * BROW   \
                                              + (kc + 1) * 32);               \
            }                                                                 \
            _Pragma("unroll") for (int mt = (MT0); mt < 5; ++mt) {            \
                acc[mt][0] = __builtin_amdgcn_mfma_f32_16x16x32_f16(          \
                    __builtin_bit_cast(f16x8, a0_), bc_[mt], acc[mt][0],      \
                    0, 0, 0);                                                 \
                acc[mt][1] = __builtin_amdgcn_mfma_f32_16x16x32_f16(          \
                    __builtin_bit_cast(f16x8, a1_), bc_[mt], acc[mt][1],      \
                    0, 0, 0);                                                 \
            }                                                                 \
            a0_ = an0_; a1_ = an1_;                                           \
            _Pragma("unroll") for (int mt = (MT0); mt < 5; ++mt)              \
                bc_[mt] = bn_[mt];                                            \
        } } while (0)

    // sigmoid update: G[token row] cols = sigm(acc + xp), packed b64 store
    #define UPDATE_G(MT0) do {                                                \
        _Pragma("unroll") for (int mt = (MT0); mt < 5; ++mt)                  \
        _Pragma("unroll") for (int nt = 0; nt < 2; ++nt) {                    \
            __half2 plo = __builtin_bit_cast(__half2, xpk[mt][nt][0]);        \
            __half2 phi = __builtin_bit_cast(__half2, xpk[mt][nt][1]);        \
            float v0 = sigm(acc[mt][nt][0] + __low2float(plo));               \
            float v1 = sigm(acc[mt][nt][1] + __high2float(plo));              \
            float v2 = sigm(acc[mt][nt][2] + __low2float(phi));               \
            float v3 = sigm(acc[mt][nt][3] + __high2float(phi));              \
            unsigned int p0 = packrte(v0, v1), p1 = packrte(v2, v3);          \
            if (mt == 0) { p0 &= killm; p1 &= killm; }                        \
            *(uint2*)(gwr + mt * 16 * BROW + nt * 16) = make_uint2(p0, p1);   \
        } } while (0)

    // ---- h = relu(embf16 @ fc1.T + fc1_b) -> Gt rows 1..80 (in place)
    RUN_GEMM(Wq, 1, 0);
    __syncthreads();                  // all waves done reading staged emb
    #pragma unroll
    for (int nt = 0; nt < 2; ++nt) {
        float4 bb = *(const float4*)(bpf + c0 + nt * 16 + q * 4);
        #pragma unroll
        for (int mt = 0; mt < 5; ++mt) {
            float v0 = fmaxf(acc[mt][nt][0] + bb.x, 0.f);
            float v1 = fmaxf(acc[mt][nt][1] + bb.y, 0.f);
            float v2 = fmaxf(acc[mt][nt][2] + bb.z, 0.f);
            float v3 = fmaxf(acc[mt][nt][3] + bb.w, 0.f);
            *(uint2*)(gwr + mt * 16 * BROW + nt * 16) =
                make_uint2(packrte(v0, v1), packrte(v2, v3));
        }
    }
    __syncthreads();

    // ---- xp = h @ l1_wx.T + l1_b, packed f16 in regs (pads = NEGB)
    RUN_GEMM(Wq + 320 * 40, 1, 0);
    #pragma unroll
    for (int nt = 0; nt < 2; ++nt) {
        float4 bb = *(const float4*)(bpl1 + c0 + nt * 16 + q * 4);
        #pragma unroll
        for (int mt = 0; mt < 5; ++mt) {
            xpk[mt][nt][0] = packrte(acc[mt][nt][0] + bb.x, acc[mt][nt][1] + bb.y);
            xpk[mt][nt][1] = packrte(acc[mt][nt][2] + bb.z, acc[mt][nt][3] + bb.w);
        }
    }
    __syncthreads();                  // all waves done reading h
    // ---- G init = sigm(xp)  (pads -> sigm(NEGB) = 0)
    #pragma unroll
    for (int mt = 0; mt < 5; ++mt)
    #pragma unroll
    for (int nt = 0; nt < 2; ++nt) {
        __half2 plo = __builtin_bit_cast(__half2, xpk[mt][nt][0]);
        __half2 phi = __builtin_bit_cast(__half2, xpk[mt][nt][1]);
        unsigned int p0 = packrte(sigm(__low2float(plo)), sigm(__high2float(plo)));
        unsigned int p1 = packrte(sigm(__low2float(phi)), sigm(__high2float(phi)));
        if (mt == 0) { p0 &= killm; p1 &= killm; }
        *(uint2*)(gwr + mt * 16 * BROW + nt * 16) = make_uint2(p0, p1);
    }
    __syncthreads();

    // ---- 11 fixed-point passes, all in LDS
    #pragma unroll 1
    for (int p = 0; p < NPASS; ++p) {
        if (p == NPASS - 1) {         // last pass: halo rows dead
            RUN_GEMM(Wq + 3 * 320 * 40, 0, 1);
            __syncthreads();
            UPDATE_G(1);
        } else {
            RUN_GEMM(Wq + 3 * 320 * 40, 0, 0);
            __syncthreads();
            UPDATE_G(0);
        }
        __syncthreads();
    }

    // ---- out = G @ l2.T over output tokens (mt 1..4 = rows m0..m0+63);
    //      max over tokens = in-lane over mt + shfl over ml lanes
    RUN_GEMM(Wq + 2 * 320 * 40, 1, 1);
    #pragma unroll
    for (int nt = 0; nt < 2; ++nt)
    #pragma unroll
    for (int r = 0; r < 4; ++r) {
        float v = acc[1][nt][r];
        v = fmaxf(v, acc[2][nt][r]);
        v = fmaxf(v, acc[3][nt][r]);
        v = fmaxf(v, acc[4][nt][r]);
        v = fmaxf(v, __shfl_xor(v, 1));
        v = fmaxf(v, __shfl_xor(v, 2));
        v = fmaxf(v, __shfl_xor(v, 4));
        v = fmaxf(v, __shfl_xor(v, 8));
        if (ml == 0) {
            int col = c0 + nt * 16 + q * 4 + r;
            part[(long)blockIdx.x * 320 + col] = v + bpl2[col];
        }
    }
    #undef RUN_GEMM
    #undef UPDATE_G
}

// =====================================================================
// Final: pooled[b,n] = max over 8 m-chunks of part; out = pooled @ fc2_w.T
// =====================================================================
__global__ __launch_bounds__(320) void fc2_final(
    const float* __restrict__ part,     // [512, 320]
    const float* __restrict__ fc2_w,
    const float* __restrict__ fc2_b,
    float* __restrict__ out)
{
    const int b   = blockIdx.x;
    const int tid = threadIdx.x;
    __shared__ float pooled[304];

    if (tid < 300) {
        float m = part[(long)(b * 8) * 320 + tid];
        #pragma unroll
        for (int c = 1; c < 8; c++)
            m = fmaxf(m, part[(long)(b * 8 + c) * 320 + tid]);
        pooled[tid] = m;
    }
    __syncthreads();

    const int o    = tid >> 6;
    const int lane = tid & 63;
    if (o < 2) {
        float sacc = 0.f;
        for (int jj = lane; jj < 300; jj += 64)
            sacc += pooled[jj] * fc2_w[o * 300 + jj];
        #pragma unroll
        for (int off = 32; off > 0; off >>= 1)
            sacc += __shfl_down(sacc, off);
        if (lane == 0) out[b * 2 + o] = sacc + fc2_b[o];
    }
}

// =====================================================================
extern "C" void kernel_launch(void* const* d_in, const int* in_sizes, int n_in,
                              void* d_out, int out_size, void* d_ws, size_t ws_size,
                              hipStream_t stream)
{
    const int*   x     = (const int*)  d_in[0];
    const float* emb   = (const float*)d_in[1];
    const float* fc1_w = (const float*)d_in[2];
    const float* fc1_b = (const float*)d_in[3];
    const float* l1_w  = (const float*)d_in[4];
    const float* l1_b  = (const float*)d_in[5];
    const float* l2_w  = (const float*)d_in[6];
    const float* l2_b  = (const float*)d_in[7];
    const float* fc2_w = (const float*)d_in[8];
    const float* fc2_b = (const float*)d_in[9];
    float* out = (float*)d_out;

    // ws: part [512*320 f32] | Wh [4*320*160 uints] | BP [960 f32]
    float* part = (float*)d_ws;
    unsigned int* Wh = (unsigned int*)(part + (size_t)512 * 320);
    float* BP = (float*)(Wh + (size_t)4 * 320 * HSTR);

    wconv<<<dim3(320, 5), 160, 0, stream>>>(
        fc1_w, l1_w, l2_w, fc1_b, l1_b, l2_b, Wh, BP);
    rnn_mega<<<M_TOT / 64, 640, 0, stream>>>(x, emb, BP, Wh, part);
    fc2_final<<<B_SZ, 320, 0, stream>>>(part, fc2_w, fc2_b, out);
}

// Round 9
// 364.164 us; speedup vs baseline: 1.7165x; 1.6634x over previous
//
#include <hip/hip_runtime.h>
#include <hip/hip_fp16.h>
#include <math.h>

#define B_SZ 64
#define T_SZ 512
#define M_TOT (B_SZ * T_SZ)   // 32768 tokens
#define HSTR  160             // uints per weight row (320 halves; rows/cols >=300 zero)
#define NPASS 11              // fixed-point refinement passes (halo 16 >= NPASS)
#define BROW  328             // halves per LDS G row: 656B = 41*16 -> b128 reads ALIGNED
                              // (r8 lesson: BROW=332 misaligns ds_read_b128 -> ~2x LDS time)
#define BUF1  (81 * BROW)     // element offset of second G buffer
#define NEGB  -60000.0f       // pad-bias poison: relu->0, sigm->0

typedef _Float16 f16x8 __attribute__((ext_vector_type(8)));
typedef float    f32x4 __attribute__((ext_vector_type(4)));

__device__ __forceinline__ unsigned int packrte(float a, float b) {
    __half2 h = __floats2half2_rn(a, b);
    return __builtin_bit_cast(unsigned int, h);
}
// rcp-based sigmoid (validated r6/r7/r8: absmax bit-identical, VALU halved).
// Output is f16-rounded downstream; pads: exp(60000)=inf -> rcp(inf)=0.
__device__ __forceinline__ float sigm(float v) {
    return __builtin_amdgcn_rcpf(1.f + __expf(-v));
}

// =====================================================================
// Weights fp32 -> packed f16x2, zero-padded to 320x320.  m=4: padded
// bias vectors (pads poisoned with NEGB so relu/sigm give exact 0).
// =====================================================================
__global__ __launch_bounds__(160) void wconv(
    const float* __restrict__ fc1_w, const float* __restrict__ l1_w,
    const float* __restrict__ l2_w, const float* __restrict__ fc1_b,
    const float* __restrict__ l1_b, const float* __restrict__ l2_b,
    unsigned int* __restrict__ Wh, float* __restrict__ BP)
{
    const int r = blockIdx.x, m = blockIdx.y, j = threadIdx.x;
    if (m == 4) {
        if (j == 0) BP[r]       = (r < 300) ? fc1_b[r] : NEGB;
        if (j == 1) BP[320 + r] = (r < 300) ? l1_b[r]  : NEGB;
        if (j == 2) BP[640 + r] = (r < 300) ? l2_b[r]  : 0.f;
        return;
    }
    const float* src; int stride, off;
    if (m == 0)      { src = fc1_w; stride = 300; off = 0; }
    else if (m == 1) { src = l1_w;  stride = 600; off = 0; }
    else if (m == 2) { src = l2_w;  stride = 300; off = 0; }
    else             { src = l1_w;  stride = 600; off = 300; }
    int k = 2 * j;
    bool rv = (r < 300);
    float a = (rv && k     < 300) ? src[(long)r * stride + off + k]     : 0.f;
    float b = (rv && k + 1 < 300) ? src[(long)r * stride + off + k + 1] : 0.f;
    Wh[((long)m * 320 + r) * HSTR + j] = packrte(a, b);
}

// =====================================================================
// Fused per-64-row-tile kernel: 10 waves (640 thr), round-4 register
// shape (VGPR 84, no spill) + PING-PONG G buffers with COMPILE-TIME
// buffer offsets (pass loop unrolled by 2): one barrier per RNN pass.
// BROW=328 keeps all ds_read_b128 16B-aligned; rcp-sigmoid.
// Swapped MFMA: A = weight frag (16 out cols), B = G frag (16 tokens).
// D: col(ml)=token, row(q*4+r)=out col -> packed ds_write_b64 updates.
// Wave owns 32 output cols (nt=2), loops all 5 m-tiles.
// =====================================================================
__global__ __launch_bounds__(640, 3) void rnn_mega(
    const int* __restrict__ x, const float* __restrict__ emb,
    const float* __restrict__ BP, const unsigned int* __restrict__ Wh,
    float* __restrict__ part)
{
    __shared__ _Float16 Gt[2 * 81 * BROW];   // row 0 of each buf = zero row

    const int tid  = threadIdx.x;
    const int lane = tid & 63;
    const int ml   = lane & 15;
    const int q    = lane >> 4;
    const int c0   = (tid >> 6) * 32;    // wave's 32 output cols
    const int m0   = blockIdx.x * 64;
    const int m0h  = m0 - 16;
    const bool bstart = (m0 & (T_SZ - 1)) == 0;
    const unsigned int killm = (bstart && ml == 15) ? 0u : ~0u;  // row t=m0-1

    const uint4* Wq = (const uint4*)Wh;             // 40 uint4 per row
    const float* bpf  = BP;
    const float* bpl1 = BP + 320;
    const float* bpl2 = BP + 640;

    // per-wave LDS bases; buffer select = +0 / +BUF1 compile-time offset
    const _Float16* grd = &Gt[ml * BROW + q * 8];             // B-frag reads
    _Float16*       gwr = &Gt[(ml + 1) * BROW + c0 + q * 4];  // update writes

    // ---- stage emb[x[m0h..m0h+80)] as f16 into buf0 rows 1..80
    #pragma unroll
    for (int it = 0; it < 5; ++it) {
        int li  = it * 640 + tid;      // 0..3199
        int row = li / 40;             // 0..79
        int sg  = li % 40;             // 8-half segment
        int g   = m0h + row; if (g < 0) g = 0;   // block 0 halo clamp
        const float* er = emb + (long)x[g] * 300;
        int k = sg * 8;
        float4 f0 = (k + 4 <= 300) ? *(const float4*)(er + k)     : make_float4(0,0,0,0);
        float4 f1 = (k + 8 <= 300) ? *(const float4*)(er + k + 4) : make_float4(0,0,0,0);
        *(uint4*)&Gt[(row + 1) * BROW + sg * 8] =
            make_uint4(packrte(f0.x, f0.y), packrte(f0.z, f0.w),
                       packrte(f1.x, f1.y), packrte(f1.z, f1.w));
    }
    // zero row 0 of both buffers (41 uint4 = 328 halves each, exact)
    if (tid < 41) {
        *(uint4*)&Gt[tid * 8]        = make_uint4(0, 0, 0, 0);
        *(uint4*)&Gt[BUF1 + tid * 8] = make_uint4(0, 0, 0, 0);
    }
    __syncthreads();

    f32x4        acc[5][2];
    unsigned int xpk[5][2][2];

    // GEMM: acc[mt][nt] = W(rows c0+nt*16..) @ GtBOFF(rows mt*16+ml+RO).T
    // A-frags (weights) from L2, B-frags ds_read_b128 at immediate
    // offsets, both register-double-buffered one kc ahead.
    #define RUN_GEMM(WQ, RO, MT0, BOFF) do {                                  \
        _Pragma("unroll") for (int mt = (MT0); mt < 5; ++mt)                  \
        _Pragma("unroll") for (int nt = 0; nt < 2; ++nt)                      \
            acc[mt][nt] = (f32x4){0.f, 0.f, 0.f, 0.f};                        \
        const uint4* wp0_ = (WQ) + (c0 + ml) * 40 + q;                        \
        const uint4* wp1_ = wp0_ + 640;                                       \
        uint4 a0_ = wp0_[0], a1_ = wp1_[0];                                   \
        f16x8 bc_[5];                                                         \
        _Pragma("unroll") for (int mt = (MT0); mt < 5; ++mt)                  \
            bc_[mt] = *(const f16x8*)(grd + (BOFF) + (mt * 16 + (RO)) * BROW);\
        _Pragma("unroll") for (int kc = 0; kc < 10; ++kc) {                   \
            uint4 an0_, an1_; f16x8 bn_[5];                                   \
            if (kc < 9) {                                                     \
                an0_ = wp0_[(kc + 1) * 4];                                    \
                an1_ = wp1_[(kc + 1) * 4];                                    \
                _Pragma("unroll") for (int mt = (MT0); mt < 5; ++mt)          \
                    bn_[mt] = *(const f16x8*)(grd + (BOFF)                    \
                              + (mt * 16 + (RO)) * BROW + (kc + 1) * 32);     \
            }                                                                 \
            _Pragma("unroll") for (int mt = (MT0); mt < 5; ++mt) {            \
                acc[mt][0] = __builtin_amdgcn_mfma_f32_16x16x32_f16(          \
                    __builtin_bit_cast(f16x8, a0_), bc_[mt], acc[mt][0],      \
                    0, 0, 0);                                                 \
                acc[mt][1] = __builtin_amdgcn_mfma_f32_16x16x32_f16(          \
                    __builtin_bit_cast(f16x8, a1_), bc_[mt], acc[mt][1],      \
                    0, 0, 0);                                                 \
            }                                                                 \
            a0_ = an0_; a1_ = an1_;                                           \
            _Pragma("unroll") for (int mt = (MT0); mt < 5; ++mt)              \
                bc_[mt] = bn_[mt];                                            \
        } } while (0)

    // sigmoid update into buffer BOFF: G = sigm(acc + xp), packed b64
    #define UPDATE_G(MT0, BOFF) do {                                          \
        _Pragma("unroll") for (int mt = (MT0); mt < 5; ++mt)                  \
        _Pragma("unroll") for (int nt = 0; nt < 2; ++nt) {                    \
            __half2 plo = __builtin_bit_cast(__half2, xpk[mt][nt][0]);        \
            __half2 phi = __builtin_bit_cast(__half2, xpk[mt][nt][1]);        \
            float v0 = sigm(acc[mt][nt][0] + __low2float(plo));               \
            float v1 = sigm(acc[mt][nt][1] + __high2float(plo));              \
            float v2 = sigm(acc[mt][nt][2] + __low2float(phi));               \
            float v3 = sigm(acc[mt][nt][3] + __high2float(phi));              \
            unsigned int p0 = packrte(v0, v1), p1 = packrte(v2, v3);          \
            if (mt == 0) { p0 &= killm; p1 &= killm; }                        \
            *(uint2*)(gwr + (BOFF) + mt * 16 * BROW + nt * 16) =              \
                make_uint2(p0, p1);                                           \
        } } while (0)

    // ---- h = relu(embf16 @ fc1.T + fc1_b): read buf0 (emb), write buf1
    RUN_GEMM(Wq, 1, 0, 0);
    #pragma unroll
    for (int nt = 0; nt < 2; ++nt) {
        float4 bb = *(const float4*)(bpf + c0 + nt * 16 + q * 4);
        #pragma unroll
        for (int mt = 0; mt < 5; ++mt) {
            float v0 = fmaxf(acc[mt][nt][0] + bb.x, 0.f);
            float v1 = fmaxf(acc[mt][nt][1] + bb.y, 0.f);
            float v2 = fmaxf(acc[mt][nt][2] + bb.z, 0.f);
            float v3 = fmaxf(acc[mt][nt][3] + bb.w, 0.f);
            *(uint2*)(gwr + BUF1 + mt * 16 * BROW + nt * 16) =
                make_uint2(packrte(v0, v1), packrte(v2, v3));
        }
    }
    __syncthreads();                  // h (buf1) visible to all waves

    // ---- xp = h @ l1_wx.T + l1_b (read buf1) -> packed f16 regs;
    //      G^0 = sigm(xp) -> buf0 (emb dead).  Disjoint buffers: no
    //      barrier needed between the reads and these writes.
    RUN_GEMM(Wq + 320 * 40, 1, 0, BUF1);
    #pragma unroll
    for (int nt = 0; nt < 2; ++nt) {
        float4 bb = *(const float4*)(bpl1 + c0 + nt * 16 + q * 4);
        #pragma unroll
        for (int mt = 0; mt < 5; ++mt) {
            xpk[mt][nt][0] = packrte(acc[mt][nt][0] + bb.x, acc[mt][nt][1] + bb.y);
            xpk[mt][nt][1] = packrte(acc[mt][nt][2] + bb.z, acc[mt][nt][3] + bb.w);
        }
    }
    #pragma unroll
    for (int mt = 0; mt < 5; ++mt)
    #pragma unroll
    for (int nt = 0; nt < 2; ++nt) {
        __half2 plo = __builtin_bit_cast(__half2, xpk[mt][nt][0]);
        __half2 phi = __builtin_bit_cast(__half2, xpk[mt][nt][1]);
        unsigned int p0 = packrte(sigm(__low2float(plo)), sigm(__high2float(plo)));
        unsigned int p1 = packrte(sigm(__low2float(phi)), sigm(__high2float(phi)));
        if (mt == 0) { p0 &= killm; p1 &= killm; }
        *(uint2*)(gwr + mt * 16 * BROW + nt * 16) = make_uint2(p0, p1);
    }
    __syncthreads();                  // G^0 (buf0) visible

    // ---- 11 fixed-point passes, ping-pong, ONE barrier per pass.
    //      even p: read buf0 -> write buf1; odd p: read buf1 -> write buf0.
    //      Unrolled by 2 so buffer offsets are compile-time immediates.
    #pragma unroll 1
    for (int pp = 0; pp < (NPASS - 1) / 2; ++pp) {   // passes 0..9
        RUN_GEMM(Wq + 3 * 320 * 40, 0, 0, 0);
        UPDATE_G(0, BUF1);
        __syncthreads();
        RUN_GEMM(Wq + 3 * 320 * 40, 0, 0, BUF1);
        UPDATE_G(0, 0);
        __syncthreads();
    }
    // pass 10 (last, even: read buf0 -> write buf1; halo rows dead)
    RUN_GEMM(Wq + 3 * 320 * 40, 0, 1, 0);
    UPDATE_G(1, BUF1);
    __syncthreads();

    // ---- out = G @ l2.T over output tokens (final G in buf1);
    //      max over tokens = in-lane over mt + shfl over ml lanes
    RUN_GEMM(Wq + 2 * 320 * 40, 1, 1, BUF1);
    #pragma unroll
    for (int nt = 0; nt < 2; ++nt)
    #pragma unroll
    for (int r = 0; r < 4; ++r) {
        float v = acc[1][nt][r];
        v = fmaxf(v, acc[2][nt][r]);
        v = fmaxf(v, acc[3][nt][r]);
        v = fmaxf(v, acc[4][nt][r]);
        v = fmaxf(v, __shfl_xor(v, 1));
        v = fmaxf(v, __shfl_xor(v, 2));
        v = fmaxf(v, __shfl_xor(v, 4));
        v = fmaxf(v, __shfl_xor(v, 8));
        if (ml == 0) {
            int col = c0 + nt * 16 + q * 4 + r;
            part[(long)blockIdx.x * 320 + col] = v + bpl2[col];
        }
    }
    #undef RUN_GEMM
    #undef UPDATE_G
}

// =====================================================================
// Final: pooled[b,n] = max over 8 m-chunks of part; out = pooled @ fc2_w.T
// =====================================================================
__global__ __launch_bounds__(320) void fc2_final(
    const float* __restrict__ part,     // [512, 320]
    const float* __restrict__ fc2_w,
    const float* __restrict__ fc2_b,
    float* __restrict__ out)
{
    const int b   = blockIdx.x;
    const int tid = threadIdx.x;
    __shared__ float pooled[304];

    if (tid < 300) {
        float m = part[(long)(b * 8) * 320 + tid];
        #pragma unroll
        for (int c = 1; c < 8; c++)
            m = fmaxf(m, part[(long)(b * 8 + c) * 320 + tid]);
        pooled[tid] = m;
    }
    __syncthreads();

    const int o    = tid >> 6;
    const int lane = tid & 63;
    if (o < 2) {
        float sacc = 0.f;
        for (int jj = lane; jj < 300; jj += 64)
            sacc += pooled[jj] * fc2_w[o * 300 + jj];
        #pragma unroll
        for (int off = 32; off > 0; off >>= 1)
            sacc += __shfl_down(sacc, off);
        if (lane == 0) out[b * 2 + o] = sacc + fc2_b[o];
    }
}

// =====================================================================
extern "C" void kernel_launch(void* const* d_in, const int* in_sizes, int n_in,
                              void* d_out, int out_size, void* d_ws, size_t ws_size,
                              hipStream_t stream)
{
    const int*   x     = (const int*)  d_in[0];
    const float* emb   = (const float*)d_in[1];
    const float* fc1_w = (const float*)d_in[2];
    const float* fc1_b = (const float*)d_in[3];
    const float* l1_w  = (const float*)d_in[4];
    const float* l1_b  = (const float*)d_in[5];
    const float* l2_w  = (const float*)d_in[6];
    const float* l2_b  = (const float*)d_in[7];
    const float* fc2_w = (const float*)d_in[8];
    const float* fc2_b = (const float*)d_in[9];
    float* out = (float*)d_out;

    // ws: part [512*320 f32] | Wh [4*320*160 uints] | BP [960 f32]
    float* part = (float*)d_ws;
    unsigned int* Wh = (unsigned int*)(part + (size_t)512 * 320);
    float* BP = (float*)(Wh + (size_t)4 * 320 * HSTR);

    wconv<<<dim3(320, 5), 160, 0, stream>>>(
        fc1_w, l1_w, l2_w, fc1_b, l1_b, l2_b, Wh, BP);
    rnn_mega<<<M_TOT / 64, 640, 0, stream>>>(x, emb, BP, Wh, part);
    fc2_final<<<B_SZ, 320, 0, stream>>>(part, fc2_w, fc2_b, out);
}